// Round 17
// baseline (1403.163 us; speedup 1.0000x reference)
//
#include <hip/hip_runtime.h>

#define LL 128      // memory length
#define BB 16       // batch
#define HH 512      // hidden
#define VV 16000    // vocab
#define TT 32       // steps
#define NH 8        // heads
#define DK 64       // head dim

// workspace layout (float offsets)
#define WS_K 0
#define WS_V (LL*BB*HH)
#define WS_HID0 (2*LL*BB*HH)
#define WS_HID1 (WS_HID0 + BB*HH)
#define WS_CTX  (WS_HID1 + BB*HH)
#define WS_P    (WS_CTX + BB*HH)          // p[b][h][128]
#define WS_HS   (WS_P + BB*NH*LL)         // h_new in [k][b] layout (512*16)
#define WS_CAND (WS_HS + BB*HH + 16)      // u64 cand[512][16] (8B aligned)
#define WS_WFP  (WS_CAND + 2*512*BB)      // packed Wf tiles [250][512][64]

#define OUT_HID_OFF ((size_t)TT*BB*VV)
#define OUT_SC_OFF  (OUT_HID_OFF + (size_t)TT*BB*HH)

typedef unsigned long long u64;
__device__ __forceinline__ u64 u64max(u64 a, u64 b) { return a > b ? a : b; }

// cand[m][b]: hi32 = monotonic float encoding, lo32 = 0xFFFFFFFF - col.
// max over m -> max logit, tie -> smallest col (jnp.argmax first occurrence).

// K|V projection + Wf pack: grid 2298.
__global__ __launch_bounds__(256) void kv_kernel(const float* __restrict__ mem,
        const float* __restrict__ Wk, const float* __restrict__ bk,
        const float* __restrict__ Wv, const float* __restrict__ bv,
        const float* __restrict__ Wf, float* __restrict__ ws) {
    int blk = blockIdx.x;
    int tid = threadIdx.x;

    if (blk >= 2048) {          // ---- Wf pack: m = blk-2048, cols [m*64, +64)
        int m = blk - 2048;
        int colb = m * 64;
        float* dst = ws + WS_WFP + (size_t)m*32768;
        #pragma unroll
        for (int j = 0; j < 32; ++j) {
            int i = tid + 256*j;            // 8192 float4
            int k = i >> 4, c4 = i & 15;
            float4 v = *(const float4*)(Wf + (size_t)k*VV + colb + c4*4);
            *(float4*)(dst + (size_t)k*64 + c4*4) = v;
        }
        return;
    }

    int rg = blk >> 4, ct = blk & 15;
    int isV = ct >= 8;
    int colbase = (ct & 7) * 64;
    const float* W = isV ? Wv : Wk;
    const float* bias = isV ? bv : bk;
    float* outp = ws + (isV ? WS_V : WS_K);
    int rowbase = rg * 16;
    __shared__ float As[16*516];

    {   // stage 16x512 A rows into padded LDS
        const float4* srcp = (const float4*)(mem + (size_t)rowbase*512);
        #pragma unroll
        for (int j = 0; j < 8; ++j) {
            int i = tid + 256*j;
            float4 v = srcp[i];
            int row = i >> 7, c4i = i & 127;
            *(float4*)(As + row*516 + c4i*4) = v;
        }
    }
    if (blk == 0) {
        for (int i = tid; i < BB*HH; i += 256) ws[WS_HID0 + i] = 0.f;
        u64* cand = (u64*)(ws + WS_CAND);
        for (int i = tid; i < 512*BB; i += 256) cand[i] = 0ull;
    }
    __syncthreads();

    int cq = tid & 15;
    int rq4 = (tid >> 4) & 3;
    int kq = tid >> 6;                      // 0..3: k-quarter (128 k each)
    float acc[4][4];
    #pragma unroll
    for (int i = 0; i < 4; ++i) { acc[i][0]=0.f; acc[i][1]=0.f; acc[i][2]=0.f; acc[i][3]=0.f; }
    const float* wp = W + colbase + cq*4;
    for (int k4 = kq*32; k4 < kq*32 + 32; ++k4) {
        float4 a0 = *(const float4*)(As + (rq4*4+0)*516 + k4*4);
        float4 a1 = *(const float4*)(As + (rq4*4+1)*516 + k4*4);
        float4 a2 = *(const float4*)(As + (rq4*4+2)*516 + k4*4);
        float4 a3 = *(const float4*)(As + (rq4*4+3)*516 + k4*4);
        const float* wrow = wp + (size_t)(4*k4)*512;
        float4 w0 = *(const float4*)(wrow);
        float4 w1 = *(const float4*)(wrow + 512);
        float4 w2 = *(const float4*)(wrow + 1024);
        float4 w3 = *(const float4*)(wrow + 1536);
        #define KV_FMA(ri, A) \
            acc[ri][0] += A.x*w0.x + A.y*w1.x + A.z*w2.x + A.w*w3.x; \
            acc[ri][1] += A.x*w0.y + A.y*w1.y + A.z*w2.y + A.w*w3.y; \
            acc[ri][2] += A.x*w0.z + A.y*w1.z + A.z*w2.z + A.w*w3.z; \
            acc[ri][3] += A.x*w0.w + A.y*w1.w + A.z*w2.w + A.w*w3.w;
        KV_FMA(0, a0) KV_FMA(1, a1) KV_FMA(2, a2) KV_FMA(3, a3)
        #undef KV_FMA
    }
    __syncthreads();
    float* red = As;
    #pragma unroll
    for (int ri = 0; ri < 4; ++ri)
        *(float4*)(red + ri*1024 + tid*4) =
            make_float4(acc[ri][0], acc[ri][1], acc[ri][2], acc[ri][3]);
    __syncthreads();
    {
        int c4 = tid & 15, row = tid >> 4;
        int rq = row >> 2, ri = row & 3;
        float4 b4v = *(const float4*)(bias + colbase + c4*4);
        float o[4] = {b4v.x, b4v.y, b4v.z, b4v.w};
        #pragma unroll
        for (int kq2 = 0; kq2 < 4; ++kq2) {
            const float* pr = red + ri*1024 + (kq2*64 + rq*16 + c4)*4;
            o[0] += pr[0]; o[1] += pr[1]; o[2] += pr[2]; o[3] += pr[3];
        }
        *(float4*)(outp + (size_t)(rowbase + row)*512 + colbase + c4*4) =
            make_float4(o[0], o[1], o[2], o[3]);
    }
}

// Attention: 128 blocks = (b,h), 256 threads. cand-resolve + qproj + scores
// + softmax + ctx.
__global__ __launch_bounds__(256) void attn_kernel(
        const float* __restrict__ emb, const float* __restrict__ Wq,
        const float* __restrict__ bq, float* __restrict__ ws, int t) {
    int b = blockIdx.x >> 3, h = blockIdx.x & 7;
    int tid = threadIdx.x;
    const float* hid = ws + ((t & 1) ? WS_HID1 : WS_HID0);
    __shared__ float q[2*HH];
    __shared__ float part[4*64];
    __shared__ float qh[64];
    __shared__ float sp[2*LL];
    __shared__ float p[LL];
    __shared__ float cpart[4*64];
    __shared__ unsigned idx_s;

    if (t > 0) {   // resolve argmax from 512 (padded) block candidates
        if (tid < 64) {
            const u64* cp = (const u64*)(ws + WS_CAND) + b;
            u64 m = 0ull;
            #pragma unroll
            for (int j = 0; j < 8; ++j)
                m = u64max(m, cp[(size_t)(tid + 64*j)*BB]);
            #pragma unroll
            for (int off = 32; off; off >>= 1)
                m = u64max(m, (u64)__shfl_xor((long long)m, off));
            if (tid == 0) idx_s = 0xFFFFFFFFu - (unsigned)(m & 0xFFFFFFFFull);
        }
    } else if (tid == 0) idx_s = 0u;
    __syncthreads();
    unsigned idx = idx_s;
    for (int i = tid; i < HH; i += 256) {
        q[i] = emb[(size_t)idx*HH + i];
        q[HH + i] = hid[b*HH + i];
    }
    __syncthreads();

    {   // qproj: c4 = tid&15 (4 cols), kc = tid>>4 (16 slices); k = kc + 16*i
        int c4 = tid & 15, kc = tid >> 4;
        const float* wp = Wq + (size_t)kc*HH + h*64 + c4*4;
        float ax=0.f, ay=0.f, az=0.f, aw=0.f;
        #pragma unroll 8
        for (int i = 0; i < 64; ++i) {
            float x = q[kc + 16*i];
            float4 w4 = *(const float4*)wp;
            wp += (size_t)16*HH;
            ax += x*w4.x; ay += x*w4.y; az += x*w4.z; aw += x*w4.w;
        }
        float v;
        v = ax; v += __shfl_xor(v,16); v += __shfl_xor(v,32); ax = v;
        v = ay; v += __shfl_xor(v,16); v += __shfl_xor(v,32); ay = v;
        v = az; v += __shfl_xor(v,16); v += __shfl_xor(v,32); az = v;
        v = aw; v += __shfl_xor(v,16); v += __shfl_xor(v,32); aw = v;
        int wv = tid >> 6;
        if ((tid & 48) == 0)
            *(float4*)(part + wv*64 + c4*4) = make_float4(ax, ay, az, aw);
    }
    __syncthreads();
    if (tid < 64) {
        float s = bq[h*64 + tid];
        #pragma unroll
        for (int wv = 0; wv < 4; ++wv) s += part[wv*64 + tid];
        qh[tid] = s;
    }
    __syncthreads();

    {   // scores: thread = (l 0..127, jh 0..1)
        int l = tid & 127, jh = tid >> 7;
        const float4* kr = (const float4*)(ws + WS_K + ((size_t)(l*BB + b))*HH + h*DK) + jh*8;
        const float4* q4 = (const float4*)qh + jh*8;
        float acc = 0.f;
        #pragma unroll
        for (int j = 0; j < 8; ++j) {
            float4 kv = kr[j], qq = q4[j];
            acc += qq.x*kv.x + qq.y*kv.y + qq.z*kv.z + qq.w*kv.w;
        }
        sp[jh*128 + l] = acc;
    }
    __syncthreads();

    if (tid < 64) {   // softmax over 128 by wave 0
        float s0 = (sp[tid]      + sp[128 + tid]) * 0.125f;
        float s1 = (sp[64 + tid] + sp[192 + tid]) * 0.125f;
        float m = fmaxf(s0, s1);
        #pragma unroll
        for (int off = 32; off; off >>= 1) m = fmaxf(m, __shfl_xor(m, off));
        float e0 = expf(s0 - m), e1 = expf(s1 - m);
        float sum = e0 + e1;
        #pragma unroll
        for (int off = 32; off; off >>= 1) sum += __shfl_xor(sum, off);
        float inv = 1.f / sum;
        p[tid]      = e0 * inv;
        p[64 + tid] = e1 * inv;
    }
    __syncthreads();
    if (tid < 128) ws[WS_P + (size_t)(b*NH + h)*LL + tid] = p[tid];

    {   // ctx: thread = (c 0..63, lc 0..3 l-slices of 32)
        int c = tid & 63, lc = tid >> 6;
        const float* Vp = ws + WS_V + h*DK + c;
        float acc = 0.f;
        #pragma unroll 8
        for (int li = 0; li < 32; ++li) {
            int l = lc*32 + li;
            acc += p[l] * Vp[(size_t)(l*BB + b)*HH];
        }
        cpart[lc*64 + c] = acc;
    }
    __syncthreads();
    if (tid < 64)
        ws[WS_CTX + b*HH + h*DK + tid] =
            cpart[tid] + cpart[64+tid] + cpart[128+tid] + cpart[192+tid];
}

// GRU gates + finalize: 32 blocks x 512 thr. Fused r/z/n per weight matrix.
__global__ __launch_bounds__(512) void gates_kernel(
        const float* __restrict__ Wih, const float* __restrict__ bih,
        const float* __restrict__ Whh, const float* __restrict__ bhh,
        const int* __restrict__ olen, float* __restrict__ ws,
        float* __restrict__ out, int t) {
    int cb = blockIdx.x;      // 0..31
    int tid = threadIdx.x;
    const float* hid_in = ws + ((t & 1) ? WS_HID1 : WS_HID0);
    float* hid_out = ws + ((t & 1) ? WS_HID0 : WS_HID1);
    const float* ctx = ws + WS_CTX;
    __shared__ float xs[512*20];      // ctx  [k][b] stride 20
    __shared__ float hh[512*20];      // hid  [k][b] stride 20
    __shared__ float part[3*8*256];   // [g][wave][b*16+c]
    __shared__ float gacc[6*256];

    for (int i = tid; i < BB*HH; i += 512) {
        int bb = i >> 9, k = i & 511;
        xs[k*20 + bb] = ctx[i];
        hh[k*20 + bb] = hid_in[i];
    }
    if (tid < 64) {   // sc output: 64 of 2048 (b,l) pairs per block
        int e = cb*64 + tid;
        int b = e >> 7, l = e & 127;
        float s = 0.f;
        #pragma unroll
        for (int hq = 0; hq < NH; ++hq)
            s += ws[WS_P + (size_t)(b*NH + hq)*LL + l];
        out[OUT_SC_OFF + ((size_t)t*BB + b)*LL + l] = (t < olen[b]) ? s*0.125f : 0.f;
    }
    __syncthreads();

    int c4 = tid & 3, b4 = (tid >> 2) & 3, kc = tid >> 4;  // 4 x 4 x 32
    int wv = tid >> 6;
    #pragma unroll
    for (int pass = 0; pass < 2; ++pass) {
        const float* W = pass ? Whh : Wih;
        const float* xsrc = pass ? hh : xs;
        float aR[4][4], aZ[4][4], aN[4][4];
        #pragma unroll
        for (int i = 0; i < 4; ++i)
            #pragma unroll
            for (int j = 0; j < 4; ++j) { aR[i][j]=0.f; aZ[i][j]=0.f; aN[i][j]=0.f; }
        const float* wp = W + (size_t)kc*(3*HH) + cb*16 + c4*4;
        const float* xp = xsrc + kc*20 + b4*4;
        #pragma unroll 4
        for (int i = 0; i < 16; ++i) {     // k = kc + 32*i
            float4 wr = *(const float4*)(wp);
            float4 wz = *(const float4*)(wp + HH);
            float4 wn = *(const float4*)(wp + 2*HH);
            float4 x4 = *(const float4*)xp;
            wp += (size_t)32*(3*HH);
            xp += 32*20;
            #define GR(bi, xv) \
                aR[bi][0] += xv*wr.x; aR[bi][1] += xv*wr.y; aR[bi][2] += xv*wr.z; aR[bi][3] += xv*wr.w; \
                aZ[bi][0] += xv*wz.x; aZ[bi][1] += xv*wz.y; aZ[bi][2] += xv*wz.z; aZ[bi][3] += xv*wz.w; \
                aN[bi][0] += xv*wn.x; aN[bi][1] += xv*wn.y; aN[bi][2] += xv*wn.z; aN[bi][3] += xv*wn.w;
            GR(0, x4.x) GR(1, x4.y) GR(2, x4.z) GR(3, x4.w)
            #undef GR
        }
        #pragma unroll
        for (int bi = 0; bi < 4; ++bi)
            #pragma unroll
            for (int ci = 0; ci < 4; ++ci) {
                float v;
                v = aR[bi][ci]; v += __shfl_xor(v,16); v += __shfl_xor(v,32); aR[bi][ci] = v;
                v = aZ[bi][ci]; v += __shfl_xor(v,16); v += __shfl_xor(v,32); aZ[bi][ci] = v;
                v = aN[bi][ci]; v += __shfl_xor(v,16); v += __shfl_xor(v,32); aN[bi][ci] = v;
            }
        if ((tid & 48) == 0) {
            #pragma unroll
            for (int bi = 0; bi < 4; ++bi) {
                *(float4*)(part + (0*8 + wv)*256 + (b4*4+bi)*16 + c4*4) =
                    make_float4(aR[bi][0], aR[bi][1], aR[bi][2], aR[bi][3]);
                *(float4*)(part + (1*8 + wv)*256 + (b4*4+bi)*16 + c4*4) =
                    make_float4(aZ[bi][0], aZ[bi][1], aZ[bi][2], aZ[bi][3]);
                *(float4*)(part + (2*8 + wv)*256 + (b4*4+bi)*16 + c4*4) =
                    make_float4(aN[bi][0], aN[bi][1], aN[bi][2], aN[bi][3]);
            }
        }
        __syncthreads();
        // 768 outputs (g, b*16+c): sum over 8 waves; strided over 512 threads
        for (int e2 = tid; e2 < 768; e2 += 512) {
            int g = e2 >> 8, e = e2 & 255;
            float s = 0.f;
            #pragma unroll
            for (int w = 0; w < 8; ++w) s += part[(g*8 + w)*256 + e];
            gacc[(pass*3 + g)*256 + e] = s;
        }
        __syncthreads();
    }

    // finalize: 256 threads, one (b, c) each
    if (tid < 256) {
        int b = tid >> 4, c = tid & 15;
        int col = cb*16 + c;
        float gir = gacc[0*256 + b*16 + c] + bih[col];
        float giz = gacc[1*256 + b*16 + c] + bih[HH + col];
        float gin = gacc[2*256 + b*16 + c] + bih[2*HH + col];
        float ghr = gacc[3*256 + b*16 + c] + bhh[col];
        float ghz = gacc[4*256 + b*16 + c] + bhh[HH + col];
        float ghn = gacc[5*256 + b*16 + c] + bhh[2*HH + col];
        float r = 1.f/(1.f + __expf(-(gir + ghr)));
        float z = 1.f/(1.f + __expf(-(giz + ghz)));
        float xn = gin + r*ghn;
        float n = 1.f - 2.f/(__expf(2.f*xn) + 1.f);
        float hprev = hh[col*20 + b];
        float hnew = (1.f - z)*n + z*hprev;
        hid_out[b*HH + col] = hnew;                                    // carry (unmasked)
        out[OUT_HID_OFF + ((size_t)t*BB + b)*HH + col] = (t < olen[b]) ? hnew : 0.f;
        ws[WS_HS + col*16 + b] = hnew;                                 // [k][b] for logits
    }
}

// Logits v4: 250 blocks x 1024 thr, 64 cols/block, packed [250][512][64] tiles.
// Deep load pipelining (4-batch register preload); wave=b final; nt out stores.
__global__ __launch_bounds__(1024) void logits_kernel(
        const float* __restrict__ bf, const int* __restrict__ olen,
        float* __restrict__ ws, float* __restrict__ out, int t) {
    __shared__ float hs[HH*20];              // 40 KB: h_new [k][b] stride 20
    __shared__ float red[16*1024];           // 64 KB: per-wave partials
    int tid = threadIdx.x;
    int lane = tid & 63, wv = tid >> 6;

    {   // stage h from ws [512][16] -> padded LDS
        const float4* s4 = (const float4*)(ws + WS_HS);
        #pragma unroll
        for (int j = 0; j < 2; ++j) {
            int i = tid + 1024*j;            // 2048 float4
            float4 v = s4[i];
            int row = i >> 2, qo = i & 3;
            *(float4*)(hs + row*20 + qo*4) = v;
        }
    }
    __syncthreads();

    int cq = lane & 15;                      // col-quad 0..15 (64 cols)
    int kc = wv*4 + (lane >> 4);             // k-slice 0..63
    int colbase = blockIdx.x * 64;
    const float* wtile = ws + WS_WFP + (size_t)blockIdx.x*32768;

    float acc[16][4];
    #pragma unroll
    for (int bi = 0; bi < 16; ++bi) { acc[bi][0]=0.f; acc[bi][1]=0.f; acc[bi][2]=0.f; acc[bi][3]=0.f; }

    #pragma unroll
    for (int half = 0; half < 2; ++half) {
        float4 wr[4];
        const float* wp = wtile + (size_t)(kc + 256*half)*64 + cq*4;
        #pragma unroll
        for (int i = 0; i < 4; ++i) { wr[i] = *(const float4*)wp; wp += 4096; }
        #pragma unroll
        for (int i = 0; i < 4; ++i) {        // k = kc + 256*half + 64*i
            int k = kc + 256*half + 64*i;
            float4 w4 = wr[i];
            const float* hp = hs + k*20;
            float4 h0 = *(const float4*)(hp);
            float4 h1 = *(const float4*)(hp + 4);
            float4 h2 = *(const float4*)(hp + 8);
            float4 h3 = *(const float4*)(hp + 12);
            #define LACC(bi, hv) acc[bi][0] += (hv)*w4.x; acc[bi][1] += (hv)*w4.y; \
                                 acc[bi][2] += (hv)*w4.z; acc[bi][3] += (hv)*w4.w;
            LACC(0,h0.x)  LACC(1,h0.y)  LACC(2,h0.z)  LACC(3,h0.w)
            LACC(4,h1.x)  LACC(5,h1.y)  LACC(6,h1.z)  LACC(7,h1.w)
            LACC(8,h2.x)  LACC(9,h2.y)  LACC(10,h2.z) LACC(11,h2.w)
            LACC(12,h3.x) LACC(13,h3.y) LACC(14,h3.z) LACC(15,h3.w)
            #undef LACC
        }
    }

    // in-wave reduce over lane bits 4,5 (the 4 kc slices within the wave)
    #pragma unroll
    for (int bi = 0; bi < 16; ++bi)
        #pragma unroll
        for (int ci = 0; ci < 4; ++ci) {
            float v = acc[bi][ci];
            v += __shfl_xor(v, 16);
            v += __shfl_xor(v, 32);
            acc[bi][ci] = v;
        }
    if ((lane & 48) == 0) {   // lanes 0..15 hold partials for col-quad cq
        #pragma unroll
        for (int bi = 0; bi < 16; ++bi)
            *(float4*)(red + wv*1024 + bi*64 + cq*4) =
                make_float4(acc[bi][0], acc[bi][1], acc[bi][2], acc[bi][3]);
    }
    __syncthreads();

    {   // final: wave = b (16 waves), lane = col (64)
        int b = wv, col = lane;
        float v = bf[colbase + col];
        #pragma unroll
        for (int w = 0; w < 16; ++w) v += red[w*1024 + b*64 + col];
        bool active = t < olen[b];
        __builtin_nontemporal_store(active ? v : 0.f,
            out + ((size_t)t*BB + b)*VV + colbase + col);
        unsigned u = __float_as_uint(v);
        u = (u & 0x80000000u) ? ~u : (u | 0x80000000u);
        u64 e = ((u64)u << 32) | (u64)(0xFFFFFFFFu - (unsigned)(colbase + col));
        #pragma unroll
        for (int off = 32; off; off >>= 1)
            e = u64max(e, (u64)__shfl_xor((long long)e, off));
        if (lane == 0)
            ((u64*)(ws + WS_CAND))[(size_t)blockIdx.x*BB + b] = e;   // plain store
    }
}

extern "C" void kernel_launch(void* const* d_in, const int* in_sizes, int n_in,
                              void* d_out, int out_size, void* d_ws, size_t ws_size,
                              hipStream_t stream) {
    const float* mem = (const float*)d_in[0];
    const float* emb = (const float*)d_in[1];
    const float* Wq  = (const float*)d_in[2];
    const float* bq  = (const float*)d_in[3];
    const float* Wk  = (const float*)d_in[4];
    const float* bk  = (const float*)d_in[5];
    const float* Wv  = (const float*)d_in[6];
    const float* bv  = (const float*)d_in[7];
    const float* Wih = (const float*)d_in[8];
    const float* bih = (const float*)d_in[9];
    const float* Whh = (const float*)d_in[10];
    const float* bhh = (const float*)d_in[11];
    const float* Wf  = (const float*)d_in[12];
    const float* bf  = (const float*)d_in[13];
    const int* olen  = (const int*)d_in[14];
    float* out = (float*)d_out;
    float* ws  = (float*)d_ws;

    hipLaunchKernelGGL(kv_kernel, dim3(2298), dim3(256), 0, stream,
                       mem, Wk, bk, Wv, bv, Wf, ws);
    for (int t = 0; t < TT; ++t) {
        hipLaunchKernelGGL(attn_kernel, dim3(BB*NH), dim3(256), 0, stream, emb, Wq, bq, ws, t);
        hipLaunchKernelGGL(gates_kernel, dim3(32), dim3(512), 0, stream,
                           Wih, bih, Whh, bhh, olen, ws, out, t);
        hipLaunchKernelGGL(logits_kernel, dim3(250), dim3(1024), 0, stream,
                           bf, olen, ws, out, t);
    }
}